// Round 1
// baseline (244.512 us; speedup 1.0000x reference)
//
#include <hip/hip_runtime.h>
#include <hip/hip_bf16.h>

#define B_   8
#define U_   8192
#define E_   256
#define N_   32
#define S_   1024          // 32*32 cells per batch
#define MP_  40
#define H_   8
#define HD_  32
#define NLIST 39           // MP-1 point slots; slot 39 = on-grid/fake token

// ---------------------------------------------------------------- K1: bucket build
__global__ void build_lists(const float* __restrict__ xc_off,
                            int* __restrict__ counts, int* __restrict__ lists) {
    int t = blockIdx.x * blockDim.x + threadIdx.x;
    if (t >= B_ * U_) return;
    int b = t >> 13;           // / U_
    int u = t & (U_ - 1);
    float x = xc_off[2 * t];
    float y = xc_off[2 * t + 1];
    // jnp.round = round-half-to-even -> rintf (v_rndne_f32)
    int row = (int)rintf(x * (float)(N_ - 1)); row = min(max(row, 0), N_ - 1);
    int col = (int)rintf(y * (float)(N_ - 1)); col = min(max(col, 0), N_ - 1);
    int g = b * S_ + row * N_ + col;
    int old = atomicAdd(&counts[g], 1);
    if (old < NLIST) lists[g * NLIST + old] = u;
}

// ---------------------------------------------------------------- K2: qk precompute
// qk[s,h,e] = (1/sqrt(hd)) * sum_d q[s, h*32+d] * Wk[e, h*32+d]
// with q[s,c] = sum_f latents[s,f] * Wq[f,c]
#define STILE 16
__global__ __launch_bounds__(256)
void compute_qk(const float* __restrict__ latents, const float* __restrict__ Wq,
                const float* __restrict__ Wk, float* __restrict__ qk) {
    __shared__ float lat[STILE][E_];
    __shared__ float q[STILE][E_];
    int s0 = blockIdx.x * STILE;
    int tid = threadIdx.x;
    for (int j = 0; j < STILE; ++j) lat[j][tid] = latents[(s0 + j) * E_ + tid];
    __syncthreads();
    // q phase: thread = output column e = tid, 16 cells at once (Wq read once/block)
    float acc[STILE];
    #pragma unroll
    for (int j = 0; j < STILE; ++j) acc[j] = 0.f;
    for (int f = 0; f < E_; ++f) {
        float wq = Wq[f * E_ + tid];
        #pragma unroll
        for (int j = 0; j < STILE; ++j) acc[j] += lat[j][f] * wq;
    }
    for (int j = 0; j < STILE; ++j) q[j][tid] = acc[j];
    __syncthreads();
    const float invs = 0.17677669529663687f;  // 1/sqrt(32)
    for (int h = 0; h < H_; ++h) {
        float a2[STILE];
        #pragma unroll
        for (int j = 0; j < STILE; ++j) a2[j] = 0.f;
        for (int d = 0; d < HD_; ++d) {
            int c = h * HD_ + d;
            float wk = Wk[tid * E_ + c];   // each lane streams its own Wk row
            #pragma unroll
            for (int j = 0; j < STILE; ++j) a2[j] += q[j][c] * wk;
        }
        for (int j = 0; j < STILE; ++j)
            qk[((size_t)(s0 + j) * H_ + h) * E_ + tid] = a2[j] * invs;
    }
}

// ---------------------------------------------------------------- K3: fused per-cell attention
__global__ __launch_bounds__(256)
void attn_cell(const float* __restrict__ zc_off, const float* __restrict__ zc_on,
               const float* __restrict__ fake, const float* __restrict__ qk,
               const float* __restrict__ Wv, const float* __restrict__ Wo,
               const int* __restrict__ counts, const int* __restrict__ lists,
               const int* __restrict__ ig_p, float* __restrict__ out) {
    __shared__ float qk_s[H_ * E_];     // 8 KB
    __shared__ float tok[MP_ * E_];     // 40 KB; reused as w[H_][E_] later
    __shared__ float sc[H_ * MP_];      // scores -> attn weights
    __shared__ float ho[E_];            // head-projected output
    __shared__ int   lst[NLIST];
    __shared__ int   cnt_s;

    int g = blockIdx.x;                 // b*S + s
    int s = g & (S_ - 1);
    int b = g >> 10;
    int tid = threadIdx.x;

    for (int i = tid; i < H_ * E_; i += 256) qk_s[i] = qk[(size_t)s * (H_ * E_) + i];
    if (tid == 0) { int c = counts[g]; cnt_s = c < NLIST ? c : NLIST; }
    __syncthreads();
    int cnt = cnt_s;
    if (tid < cnt) lst[tid] = lists[g * NLIST + tid];
    __syncthreads();

    // stage tokens into LDS (one coalesced 1KB row each)
    for (int p = 0; p < cnt; ++p) {
        int u = lst[p];
        tok[p * E_ + tid] = zc_off[((size_t)b * U_ + u) * E_ + tid];
    }
    int ig = ig_p[0];
    tok[cnt * E_ + tid] = ig ? fake[tid] : zc_on[(size_t)g * E_ + tid];
    __syncthreads();
    int ntok = cnt + 1;

    // scores: thread layout (h = tid>>5, j = tid&31); reduce over e via shfl width 32
    int h = tid >> 5, j = tid & 31;
    for (int p = 0; p < ntok; ++p) {
        float part = 0.f;
        #pragma unroll
        for (int k = 0; k < 8; ++k) {
            int e = j + 32 * k;
            part += tok[p * E_ + e] * qk_s[h * E_ + e];
        }
        #pragma unroll
        for (int off = 16; off > 0; off >>= 1)
            part += __shfl_xor(part, off, 32);
        if (j == 0) sc[h * MP_ + p] = part;
    }
    __syncthreads();

    // per-head softmax (tiny: <=40 entries), threads 0..7
    if (tid < H_) {
        float m = -1e30f;
        for (int p = 0; p < ntok; ++p) m = fmaxf(m, sc[tid * MP_ + p]);
        float sum = 0.f;
        for (int p = 0; p < ntok; ++p) {
            float e0 = __expf(sc[tid * MP_ + p] - m);
            sc[tid * MP_ + p] = e0;
            sum += e0;
        }
        float inv = 1.f / sum;
        for (int p = 0; p < ntok; ++p) sc[tid * MP_ + p] *= inv;
    }
    __syncthreads();

    // w[h][e] = sum_p attn[h][p] * tok[p][e]   (8 elements per thread in regs)
    float acc[8];
    #pragma unroll
    for (int k = 0; k < 8; ++k) acc[k] = 0.f;
    for (int p = 0; p < ntok; ++p) {
        float a = sc[h * MP_ + p];
        #pragma unroll
        for (int k = 0; k < 8; ++k) acc[k] += a * tok[p * E_ + j + 32 * k];
    }
    __syncthreads();                 // all tok reads complete before reuse
    float* w = tok;                  // reuse LDS
    #pragma unroll
    for (int k = 0; k < 8; ++k) w[h * E_ + j + 32 * k] = acc[k];
    __syncthreads();

    // headout[c] = sum_e w[h(c)][e] * Wv[e][c]   (coalesced Wv columns across threads)
    {
        int c = tid, h2 = c >> 5;
        float a = 0.f;
        for (int e = 0; e < E_; ++e) a += w[h2 * E_ + e] * Wv[e * E_ + c];
        ho[c] = a;
    }
    __syncthreads();

    // out[e] = sum_c ho[c] * Wo[c][e]
    {
        int e = tid;
        float a = 0.f;
        for (int c = 0; c < E_; ++c) a += ho[c] * Wo[c * E_ + e];
        out[(size_t)g * E_ + e] = a;
    }
}

// ---------------------------------------------------------------- launch
extern "C" void kernel_launch(void* const* d_in, const int* in_sizes, int n_in,
                              void* d_out, int out_size, void* d_ws, size_t ws_size,
                              hipStream_t stream) {
    const float* xc_off  = (const float*)d_in[0];
    const float* xc_on   = (const float*)d_in[1];
    const float* zc_off  = (const float*)d_in[2];
    const float* zc_on   = (const float*)d_in[3];
    const float* latents = (const float*)d_in[4];
    const float* fake    = (const float*)d_in[5];
    const float* Wq      = (const float*)d_in[6];
    const float* Wk      = (const float*)d_in[7];
    const float* Wv      = (const float*)d_in[8];
    const float* Wo      = (const float*)d_in[9];
    const int*   ig      = (const int*)d_in[10];
    float* out = (float*)d_out;

    char* ws = (char*)d_ws;
    int*   counts = (int*)ws;                               // 8192*4      = 32 KB
    int*   lists  = (int*)(ws + 32768);                     // 8192*39*4   = 1.22 MB
    float* qk     = (float*)(ws + 32768 + 1277952 + 1024);  // 1024*8*256*4 = 8 MB (256B-aligned region start)

    // zero the per-cell counters (must happen every call; harness doesn't re-poison)
    hipMemsetAsync(counts, 0, S_ * B_ * sizeof(int), stream);

    // output 0: xc_on_grid passthrough
    hipMemcpyAsync(out, xc_on, (size_t)B_ * N_ * N_ * 2 * sizeof(float),
                   hipMemcpyDeviceToDevice, stream);

    build_lists<<<(B_ * U_) / 256, 256, 0, stream>>>(xc_off, counts, lists);
    compute_qk<<<S_ / STILE, 256, 0, stream>>>(latents, Wq, Wk, qk);
    attn_cell<<<B_ * S_, 256, 0, stream>>>(zc_off, zc_on, fake, qk, Wv, Wo,
                                           counts, lists, ig,
                                           out + (size_t)B_ * N_ * N_ * 2);
}

// Round 2
// 174.464 us; speedup vs baseline: 1.4015x; 1.4015x over previous
//
#include <hip/hip_runtime.h>
#include <hip/hip_bf16.h>

#define B_   8
#define U_   8192
#define E_   256
#define N_   32
#define S_   1024          // 32*32 cells per batch
#define MP_  40
#define H_   8
#define NLIST 39           // MP-1 point slots; slot 39 = on-grid/fake token
#define GCELLS (B_*S_)     // 8192
#define KDIM  (H_*E_)      // 2048

typedef unsigned short ushort_t;
using bf16x8 = __attribute__((ext_vector_type(8))) short;
using f32x4  = __attribute__((ext_vector_type(4))) float;

// ---------------- ws layout (bytes) ----------------
#define WS_COUNTS 0u
#define WS_LISTS  32768u                                  // 8192*39*4 = 1277952
#define WS_QK     1310720u                                // qk fp32 [1024][8][256] = 8 MB
#define WS_W      (WS_QK + 8388608u)                      // w bf16 [8192][2048]  = 32 MB
#define WS_WVOT   (WS_W + (unsigned)(GCELLS)*KDIM*2u)     // wvoT bf16 [256][2048] = 1 MB
#define WS_NEED   (WS_WVOT + 256u*KDIM*2u)                // ~44.3 MB

__device__ inline unsigned pack2_bf16(float a, float b) {
    __hip_bfloat16 x = __float2bfloat16(a), y = __float2bfloat16(b);
    return ((unsigned)(*(unsigned short*)&y) << 16) | (unsigned)(*(unsigned short*)&x);
}

// ---------------------------------------------------------------- K1: bucket build
__global__ void build_lists(const float* __restrict__ xc_off,
                            int* __restrict__ counts, int* __restrict__ lists) {
    int t = blockIdx.x * blockDim.x + threadIdx.x;
    if (t >= B_ * U_) return;
    int b = t >> 13;
    int u = t & (U_ - 1);
    float x = xc_off[2 * t];
    float y = xc_off[2 * t + 1];
    int row = (int)rintf(x * (float)(N_ - 1)); row = min(max(row, 0), N_ - 1);
    int col = (int)rintf(y * (float)(N_ - 1)); col = min(max(col, 0), N_ - 1);
    int g = b * S_ + row * N_ + col;
    int old = atomicAdd(&counts[g], 1);
    if (old < NLIST) lists[g * NLIST + old] = u;
}

// ---------------------------------------------------------------- K2: qk precompute
// qk[s,h,e] = (1/sqrt(hd)) * sum_d (lat[s]@Wq)[h*32+d] * Wk[e, h*32+d]
#define STILE 4
__global__ __launch_bounds__(256)
void compute_qk(const float* __restrict__ latents, const float* __restrict__ Wq,
                const float* __restrict__ Wk, float* __restrict__ qk) {
    __shared__ float lat[STILE][E_];
    __shared__ float q[STILE][E_];
    int s0 = blockIdx.x * STILE;
    int tid = threadIdx.x;
    for (int j = 0; j < STILE; ++j) lat[j][tid] = latents[(s0 + j) * E_ + tid];
    __syncthreads();
    float acc[STILE];
    #pragma unroll
    for (int j = 0; j < STILE; ++j) acc[j] = 0.f;
    for (int f = 0; f < E_; ++f) {
        float wq = Wq[f * E_ + tid];
        #pragma unroll
        for (int j = 0; j < STILE; ++j) acc[j] += lat[j][f] * wq;
    }
    for (int j = 0; j < STILE; ++j) q[j][tid] = acc[j];
    __syncthreads();
    const float invs = 0.17677669529663687f;  // 1/sqrt(32)
    for (int h = 0; h < H_; ++h) {
        float a2[STILE];
        #pragma unroll
        for (int j = 0; j < STILE; ++j) a2[j] = 0.f;
        for (int d = 0; d < 32; ++d) {
            int c = h * 32 + d;
            float wk = Wk[tid * E_ + c];
            #pragma unroll
            for (int j = 0; j < STILE; ++j) a2[j] += q[j][c] * wk;
        }
        for (int j = 0; j < STILE; ++j)
            qk[((size_t)(s0 + j) * H_ + h) * E_ + tid] = a2[j] * invs;
    }
}

// ---------------------------------------------------------------- K3: Wvo^T prep
// wvoT[e'][k], k=(h,e): sum_{d<32} Wv[e][32h+d] * Wo[32h+d][e'].  8 e'-cols per block.
__global__ __launch_bounds__(256)
void prep_wvo(const float* __restrict__ Wv, const float* __restrict__ Wo,
              ushort_t* __restrict__ wvoT) {
    __shared__ float woc[E_][8];
    int e0 = blockIdx.x * 8, tid = threadIdx.x;
    {
        float4 x = *(const float4*)(Wo + (size_t)tid * E_ + e0);
        float4 y = *(const float4*)(Wo + (size_t)tid * E_ + e0 + 4);
        woc[tid][0] = x.x; woc[tid][1] = x.y; woc[tid][2] = x.z; woc[tid][3] = x.w;
        woc[tid][4] = y.x; woc[tid][5] = y.y; woc[tid][6] = y.z; woc[tid][7] = y.w;
    }
    __syncthreads();
    for (int rep = 0; rep < 8; ++rep) {
        int k = rep * 256 + tid;
        int h = k >> 8, e = k & 255;
        float acc[8];
        #pragma unroll
        for (int jj = 0; jj < 8; ++jj) acc[jj] = 0.f;
        #pragma unroll
        for (int d4 = 0; d4 < 8; ++d4) {
            float4 wv = *(const float4*)(Wv + (size_t)e * E_ + h * 32 + d4 * 4);
            int dbase = h * 32 + d4 * 4;
            #pragma unroll
            for (int qd = 0; qd < 4; ++qd) {
                float wvv = (&wv.x)[qd];
                #pragma unroll
                for (int jj = 0; jj < 8; ++jj) acc[jj] += wvv * woc[dbase + qd][jj];
            }
        }
        #pragma unroll
        for (int jj = 0; jj < 8; ++jj) {
            __hip_bfloat16 hb = __float2bfloat16(acc[jj]);
            wvoT[(size_t)(e0 + jj) * KDIM + k] = *(unsigned short*)&hb;
        }
    }
}

// ---------------------------------------------------------------- K4: pool (attention-weighted sums)
__global__ __launch_bounds__(256)
void pool_cells(const float* __restrict__ zc_off, const float* __restrict__ zc_on,
                const float* __restrict__ fake, const float* __restrict__ qk,
                const int* __restrict__ counts, const int* __restrict__ lists,
                const int* __restrict__ ig_p, ushort_t* __restrict__ wout) {
    __shared__ __align__(16) float tok[MP_ * E_];   // 40 KB
    __shared__ __align__(16) float qs[KDIM];        // 8 KB, reused as w
    __shared__ float sc[H_ * MP_];
    __shared__ int lst[NLIST];
    __shared__ int cnt_s;

    int g = blockIdx.x, s = g & (S_ - 1), b = g >> 10, tid = threadIdx.x;

    const float4* qk4 = (const float4*)(qk + (size_t)s * KDIM);
    float4* qs4 = (float4*)qs;
    qs4[tid] = qk4[tid];
    qs4[tid + 256] = qk4[tid + 256];
    if (tid < NLIST) lst[tid] = lists[g * NLIST + tid];   // garbage beyond cnt unused
    if (tid == 255) { int c = counts[g]; cnt_s = c < NLIST ? c : NLIST; }
    __syncthreads();

    int cnt = cnt_s, ntok = cnt + 1;
    int ig = ig_p[0];

    // parallel float4 token staging
    float4* tok4 = (float4*)tok;
    for (int i = tid; i < ntok * 64; i += 256) {
        int p = i >> 6, q = i & 63;
        const float4* src;
        if (p < cnt)      src = (const float4*)(zc_off + ((size_t)b * U_ + lst[p]) * E_);
        else if (ig)      src = (const float4*)fake;
        else              src = (const float4*)(zc_on + (size_t)g * E_);
        tok4[(p << 6) + q] = src[q];
    }
    __syncthreads();

    // scores: thread (h = tid>>5, j = tid&31)
    int h = tid >> 5, j = tid & 31;
    const float4* qh4 = (const float4*)(qs + h * E_);
    float4 qa = qh4[2 * j], qb = qh4[2 * j + 1];
    for (int p = 0; p < ntok; ++p) {
        float4 ta = tok4[(p << 6) + 2 * j], tb = tok4[(p << 6) + 2 * j + 1];
        float part = ta.x * qa.x + ta.y * qa.y + ta.z * qa.z + ta.w * qa.w
                   + tb.x * qb.x + tb.y * qb.y + tb.z * qb.z + tb.w * qb.w;
        #pragma unroll
        for (int off = 16; off; off >>= 1) part += __shfl_xor(part, off, 32);
        if (j == 0) sc[h * MP_ + p] = part;
    }
    __syncthreads();

    // wave-parallel softmax: each 32-lane group = one head, 2 slots/lane
    {
        float v0 = (j < ntok) ? sc[h * MP_ + j] : -1e30f;
        float v1 = (j + 32 < ntok) ? sc[h * MP_ + j + 32] : -1e30f;
        float mx = fmaxf(v0, v1);
        #pragma unroll
        for (int off = 16; off; off >>= 1) mx = fmaxf(mx, __shfl_xor(mx, off, 32));
        float e0 = (j < ntok) ? __expf(v0 - mx) : 0.f;
        float e1 = (j + 32 < ntok) ? __expf(v1 - mx) : 0.f;
        float sm = e0 + e1;
        #pragma unroll
        for (int off = 16; off; off >>= 1) sm += __shfl_xor(sm, off, 32);
        float inv = 1.f / sm;
        if (j < ntok)      sc[h * MP_ + j] = e0 * inv;
        if (j + 32 < ntok) sc[h * MP_ + j + 32] = e1 * inv;
    }
    __syncthreads();

    // w[h][e] = sum_p attn[h][p] * tok[p][e];  thread (h,j) owns e = j+32k (bank-clean)
    float acc[8];
    #pragma unroll
    for (int k = 0; k < 8; ++k) acc[k] = 0.f;
    for (int p = 0; p < ntok; ++p) {
        float a = sc[h * MP_ + p];
        #pragma unroll
        for (int k = 0; k < 8; ++k) acc[k] += a * tok[(p << 8) + j + 32 * k];
    }
    float* wl = qs;   // qs reads all completed before score loop (>=2 barriers ago)
    #pragma unroll
    for (int k = 0; k < 8; ++k) wl[h * E_ + j + 32 * k] = acc[k];
    __syncthreads();

    // repack to bf16, coalesced 16B stores
    float4 f0 = ((const float4*)wl)[2 * tid];
    float4 f1 = ((const float4*)wl)[2 * tid + 1];
    uint4 o;
    o.x = pack2_bf16(f0.x, f0.y); o.y = pack2_bf16(f0.z, f0.w);
    o.z = pack2_bf16(f1.x, f1.y); o.w = pack2_bf16(f1.z, f1.w);
    ((uint4*)(wout + (size_t)g * KDIM))[tid] = o;
}

// ---------------------------------------------------------------- K5: bf16 MFMA GEMM
// C[8192][256] = A[8192][2048]bf16 @ B (given as BT[256][2048] bf16), fp32 out.
#define BM 64
#define BN 64
#define BK 64
#define LDB 72   // padded LDS row stride in bf16 elems (144 B) -> conflict-clean frag reads
__global__ __launch_bounds__(256)
void gemm_wvo(const ushort_t* __restrict__ A, const ushort_t* __restrict__ BT,
              float* __restrict__ C) {
    __shared__ ushort_t As[BM * LDB];
    __shared__ ushort_t Bs[BN * LDB];
    int tid = threadIdx.x;
    int tm = blockIdx.x >> 2, tn = blockIdx.x & 3;
    int m0 = tm * BM, n0 = tn * BN;
    int wave = tid >> 6, lane = tid & 63;
    int wr = wave >> 1, wc = wave & 1;
    int l15 = lane & 15, lg = lane >> 4;

    f32x4 acc[2][2];
    #pragma unroll
    for (int m = 0; m < 2; ++m)
        #pragma unroll
        for (int n = 0; n < 2; ++n)
            acc[m][n] = (f32x4){0.f, 0.f, 0.f, 0.f};

    int s0 = tid, s1 = tid + 256;           // 512 16B staging slots per matrix
    int r0 = s0 >> 3, u0 = s0 & 7, r1 = s1 >> 3, u1 = s1 & 7;

    for (int kt = 0; kt < KDIM; kt += BK) {
        uint4 a0 = *(const uint4*)(A  + (size_t)(m0 + r0) * KDIM + kt + u0 * 8);
        uint4 a1 = *(const uint4*)(A  + (size_t)(m0 + r1) * KDIM + kt + u1 * 8);
        uint4 b0 = *(const uint4*)(BT + (size_t)(n0 + r0) * KDIM + kt + u0 * 8);
        uint4 b1 = *(const uint4*)(BT + (size_t)(n0 + r1) * KDIM + kt + u1 * 8);
        __syncthreads();                     // previous iteration's frag reads done
        *(uint4*)(As + r0 * LDB + u0 * 8) = a0;
        *(uint4*)(As + r1 * LDB + u1 * 8) = a1;
        *(uint4*)(Bs + r0 * LDB + u0 * 8) = b0;
        *(uint4*)(Bs + r1 * LDB + u1 * 8) = b1;
        __syncthreads();
        #pragma unroll
        for (int kk = 0; kk < 2; ++kk) {
            bf16x8 af[2], bfr[2];
            #pragma unroll
            for (int m = 0; m < 2; ++m) {
                int row = wr * 32 + m * 16 + l15;
                af[m] = *(const bf16x8*)(As + row * LDB + (kk * 4 + lg) * 8);
            }
            #pragma unroll
            for (int n = 0; n < 2; ++n) {
                int row = wc * 32 + n * 16 + l15;
                bfr[n] = *(const bf16x8*)(Bs + row * LDB + (kk * 4 + lg) * 8);
            }
            #pragma unroll
            for (int m = 0; m < 2; ++m)
                #pragma unroll
                for (int n = 0; n < 2; ++n)
                    acc[m][n] = __builtin_amdgcn_mfma_f32_16x16x32_bf16(
                        af[m], bfr[n], acc[m][n], 0, 0, 0);
        }
    }
    #pragma unroll
    for (int m = 0; m < 2; ++m)
        #pragma unroll
        for (int n = 0; n < 2; ++n)
            #pragma unroll
            for (int q = 0; q < 4; ++q) {
                int row = m0 + wr * 32 + m * 16 + lg * 4 + q;
                int col = n0 + wc * 32 + n * 16 + l15;
                C[(size_t)row * E_ + col] = acc[m][n][q];
            }
}

// ---------------------------------------------------------------- fallback (round-1 fused path)
__global__ __launch_bounds__(256)
void attn_cell(const float* __restrict__ zc_off, const float* __restrict__ zc_on,
               const float* __restrict__ fake, const float* __restrict__ qk,
               const float* __restrict__ Wv, const float* __restrict__ Wo,
               const int* __restrict__ counts, const int* __restrict__ lists,
               const int* __restrict__ ig_p, float* __restrict__ out) {
    __shared__ float qk_s[H_ * E_];
    __shared__ float tok[MP_ * E_];
    __shared__ float sc[H_ * MP_];
    __shared__ float ho[E_];
    __shared__ int   lst[NLIST];
    __shared__ int   cnt_s;
    int g = blockIdx.x, s = g & (S_ - 1), b = g >> 10, tid = threadIdx.x;
    for (int i = tid; i < H_ * E_; i += 256) qk_s[i] = qk[(size_t)s * (H_ * E_) + i];
    if (tid == 0) { int c = counts[g]; cnt_s = c < NLIST ? c : NLIST; }
    __syncthreads();
    int cnt = cnt_s;
    if (tid < cnt) lst[tid] = lists[g * NLIST + tid];
    __syncthreads();
    for (int p = 0; p < cnt; ++p) tok[p * E_ + tid] = zc_off[((size_t)b * U_ + lst[p]) * E_ + tid];
    int ig = ig_p[0];
    tok[cnt * E_ + tid] = ig ? fake[tid] : zc_on[(size_t)g * E_ + tid];
    __syncthreads();
    int ntok = cnt + 1;
    int h = tid >> 5, j = tid & 31;
    for (int p = 0; p < ntok; ++p) {
        float part = 0.f;
        #pragma unroll
        for (int k = 0; k < 8; ++k) part += tok[p * E_ + j + 32 * k] * qk_s[h * E_ + j + 32 * k];
        #pragma unroll
        for (int off = 16; off; off >>= 1) part += __shfl_xor(part, off, 32);
        if (j == 0) sc[h * MP_ + p] = part;
    }
    __syncthreads();
    if (tid < H_) {
        float m = -1e30f;
        for (int p = 0; p < ntok; ++p) m = fmaxf(m, sc[tid * MP_ + p]);
        float sum = 0.f;
        for (int p = 0; p < ntok; ++p) { float e0 = __expf(sc[tid * MP_ + p] - m); sc[tid * MP_ + p] = e0; sum += e0; }
        float inv = 1.f / sum;
        for (int p = 0; p < ntok; ++p) sc[tid * MP_ + p] *= inv;
    }
    __syncthreads();
    float acc[8];
    #pragma unroll
    for (int k = 0; k < 8; ++k) acc[k] = 0.f;
    for (int p = 0; p < ntok; ++p) {
        float a = sc[h * MP_ + p];
        #pragma unroll
        for (int k = 0; k < 8; ++k) acc[k] += a * tok[p * E_ + j + 32 * k];
    }
    __syncthreads();
    float* w = tok;
    #pragma unroll
    for (int k = 0; k < 8; ++k) w[h * E_ + j + 32 * k] = acc[k];
    __syncthreads();
    { int c = tid, h2 = c >> 5; float a = 0.f;
      for (int e = 0; e < E_; ++e) a += w[h2 * E_ + e] * Wv[e * E_ + c];
      ho[c] = a; }
    __syncthreads();
    { int e = tid; float a = 0.f;
      for (int c = 0; c < E_; ++c) a += ho[c] * Wo[c * E_ + e];
      out[(size_t)g * E_ + e] = a; }
}

// ---------------------------------------------------------------- launch
extern "C" void kernel_launch(void* const* d_in, const int* in_sizes, int n_in,
                              void* d_out, int out_size, void* d_ws, size_t ws_size,
                              hipStream_t stream) {
    const float* xc_off  = (const float*)d_in[0];
    const float* xc_on   = (const float*)d_in[1];
    const float* zc_off  = (const float*)d_in[2];
    const float* zc_on   = (const float*)d_in[3];
    const float* latents = (const float*)d_in[4];
    const float* fake    = (const float*)d_in[5];
    const float* Wq      = (const float*)d_in[6];
    const float* Wk      = (const float*)d_in[7];
    const float* Wv      = (const float*)d_in[8];
    const float* Wo      = (const float*)d_in[9];
    const int*   ig      = (const int*)d_in[10];
    float* out = (float*)d_out;

    char* ws = (char*)d_ws;
    int*      counts = (int*)(ws + WS_COUNTS);
    int*      lists  = (int*)(ws + WS_LISTS);
    float*    qk     = (float*)(ws + WS_QK);
    ushort_t* w      = (ushort_t*)(ws + WS_W);
    ushort_t* wvoT   = (ushort_t*)(ws + WS_WVOT);

    const int PASS = B_ * N_ * N_ * 2;   // xc_on_grid floats

    hipMemsetAsync(counts, 0, GCELLS * sizeof(int), stream);
    hipMemcpyAsync(out, xc_on, (size_t)PASS * sizeof(float),
                   hipMemcpyDeviceToDevice, stream);

    build_lists<<<(B_ * U_) / 256, 256, 0, stream>>>(xc_off, counts, lists);
    compute_qk<<<S_ / STILE, 256, 0, stream>>>(latents, Wq, Wk, qk);

    if (ws_size >= (size_t)WS_NEED) {
        prep_wvo<<<E_ / 8, 256, 0, stream>>>(Wv, Wo, wvoT);
        pool_cells<<<GCELLS, 256, 0, stream>>>(zc_off, zc_on, fake, qk,
                                               counts, lists, ig, w);
        gemm_wvo<<<(GCELLS / BM) * (E_ / BN), 256, 0, stream>>>(w, wvoT, out + PASS);
    } else {
        attn_cell<<<GCELLS, 256, 0, stream>>>(zc_off, zc_on, fake, qk, Wv, Wo,
                                              counts, lists, ig, out + PASS);
    }
}

// Round 4
// 125.701 us; speedup vs baseline: 1.9452x; 1.3879x over previous
//
#include <hip/hip_runtime.h>
#include <hip/hip_bf16.h>

#define B_   8
#define U_   8192
#define E_   256
#define N_   32
#define S_   1024
#define MP_  40
#define H_   8
#define NLIST 39
#define GCELLS (B_*S_)     // 8192
#define KDIM  (H_*E_)      // 2048

typedef unsigned short ushort_t;
using bf16x8 = __attribute__((ext_vector_type(8))) short;
using f32x4  = __attribute__((ext_vector_type(4))) float;

// ---------------- ws layout (bytes) — identical to round 2 (proven to fit) ----------------
#define WS_COUNTS 0u          // 8192*4 = 32768
#define WS_LISTS  32768u      // 8192*39*4 = 1277952
#define WS_QK     1310720u    // fp32 [1024][2048] = 8388608
#define WS_W      9699328u    // bf16 [8192][2048] = 33554432
#define WS_WVOT   43253760u   // bf16 [256][2048]  = 1048576   (end 44302336)

__device__ inline unsigned pk2(float a, float b) {
    __hip_bfloat16 x = __float2bfloat16(a), y = __float2bfloat16(b);
    return ((unsigned)(*(ushort_t*)&y) << 16) | (unsigned)(*(ushort_t*)&x);
}
__device__ inline float ubf(ushort_t u) {
    unsigned v = (unsigned)u << 16;
    return *(float*)&v;
}

// ================================================================ K1: fused prep
// blocks [0,256): build_lists (round-1/2 verified logic)
// blocks [256,288): prep_wvo  (round-2 verified code, verbatim)
// blocks [288,544): compute_qk (round-2 verified code, verbatim; STILE=4)
#define STILE 4
__global__ __launch_bounds__(256)
void mega_prep(const float* __restrict__ xc_off, const float* __restrict__ latents,
               const float* __restrict__ Wq, const float* __restrict__ Wk,
               const float* __restrict__ Wv, const float* __restrict__ Wo,
               int* __restrict__ counts, int* __restrict__ lists,
               float* __restrict__ qk, ushort_t* __restrict__ wvoT) {
    __shared__ float smem[2048];   // 8 KB, reused per branch
    int blk = blockIdx.x, tid = threadIdx.x;

    if (blk < 256) {                                    // ---- build_lists
        int t = blk * 256 + tid;
        float x = xc_off[2 * t], y = xc_off[2 * t + 1];
        int row = (int)rintf(x * 31.f); row = min(max(row, 0), 31);
        int col = (int)rintf(y * 31.f); col = min(max(col, 0), 31);
        int b = t >> 13;
        int g = b * S_ + row * N_ + col;
        int old = atomicAdd(&counts[g], 1);
        if (old < NLIST) lists[g * NLIST + old] = t & (U_ - 1);
    } else if (blk < 288) {                             // ---- prep_wvo (r2 verbatim)
        float (*woc)[8] = reinterpret_cast<float(*)[8]>(smem);   // [256][8]
        int e0 = (blk - 256) * 8;
        {
            float4 x = *(const float4*)(Wo + (size_t)tid * E_ + e0);
            float4 y = *(const float4*)(Wo + (size_t)tid * E_ + e0 + 4);
            woc[tid][0] = x.x; woc[tid][1] = x.y; woc[tid][2] = x.z; woc[tid][3] = x.w;
            woc[tid][4] = y.x; woc[tid][5] = y.y; woc[tid][6] = y.z; woc[tid][7] = y.w;
        }
        __syncthreads();
        for (int rep = 0; rep < 8; ++rep) {
            int k = rep * 256 + tid;
            int h = k >> 8, e = k & 255;
            float acc[8];
            #pragma unroll
            for (int jj = 0; jj < 8; ++jj) acc[jj] = 0.f;
            #pragma unroll
            for (int d4 = 0; d4 < 8; ++d4) {
                float4 wv = *(const float4*)(Wv + (size_t)e * E_ + h * 32 + d4 * 4);
                int dbase = h * 32 + d4 * 4;
                #pragma unroll
                for (int qd = 0; qd < 4; ++qd) {
                    float wvv = (&wv.x)[qd];
                    #pragma unroll
                    for (int jj = 0; jj < 8; ++jj) acc[jj] += wvv * woc[dbase + qd][jj];
                }
            }
            #pragma unroll
            for (int jj = 0; jj < 8; ++jj) {
                __hip_bfloat16 hb = __float2bfloat16(acc[jj]);
                wvoT[(size_t)(e0 + jj) * KDIM + k] = *(ushort_t*)&hb;
            }
        }
    } else {                                            // ---- compute_qk (r2 verbatim)
        float (*lat)[E_] = reinterpret_cast<float(*)[E_]>(smem);        // [4][256]
        float (*q)[E_]   = reinterpret_cast<float(*)[E_]>(smem + 1024); // [4][256]
        int s0 = (blk - 288) * STILE;
        for (int j = 0; j < STILE; ++j) lat[j][tid] = latents[(s0 + j) * E_ + tid];
        __syncthreads();
        float acc[STILE];
        #pragma unroll
        for (int j = 0; j < STILE; ++j) acc[j] = 0.f;
        for (int f = 0; f < E_; ++f) {
            float wq = Wq[f * E_ + tid];
            #pragma unroll
            for (int j = 0; j < STILE; ++j) acc[j] += lat[j][f] * wq;
        }
        for (int j = 0; j < STILE; ++j) q[j][tid] = acc[j];
        __syncthreads();
        const float invs = 0.17677669529663687f;        // 1/sqrt(32)
        for (int h = 0; h < H_; ++h) {
            float a2[STILE];
            #pragma unroll
            for (int j = 0; j < STILE; ++j) a2[j] = 0.f;
            for (int d = 0; d < 32; ++d) {
                int c = h * 32 + d;
                float wk = Wk[tid * E_ + c];
                #pragma unroll
                for (int j = 0; j < STILE; ++j) a2[j] += q[j][c] * wk;
            }
            for (int j = 0; j < STILE; ++j)
                qk[((size_t)(s0 + j) * H_ + h) * E_ + tid] = a2[j] * invs;
        }
    }
}

// ================================================================ K2: pool (attention-weighted sums)
// Round-3 LDS diet (20KB bf16 tok, no qs array) + FULL barriers between phases.
__global__ __launch_bounds__(256)
void pool_cells(const float* __restrict__ zc_off, const float* __restrict__ zc_on,
                const float* __restrict__ fake, const float* __restrict__ qk,
                const int* __restrict__ counts, const int* __restrict__ lists,
                const int* __restrict__ ig_p, ushort_t* __restrict__ wout) {
    __shared__ __align__(16) ushort_t tok[MP_ * E_];   // 20 KB
    __shared__ float sc[H_ * MP_];                     // 1.25 KB
    __shared__ int lst[NLIST];
    __shared__ int cnt_s;

    int g = blockIdx.x, s = g & (S_ - 1), b = g >> 10, tid = threadIdx.x;
    int h = tid >> 5, j = tid & 31;

    // per-thread fp32 qk fragment (e = j*8 .. j*8+7), 32B/lane
    float qa[8];
    {
        const float4* qsrc = (const float4*)(qk + (size_t)s * KDIM + h * E_ + j * 8);
        float4 q0 = qsrc[0], q1 = qsrc[1];
        qa[0] = q0.x; qa[1] = q0.y; qa[2] = q0.z; qa[3] = q0.w;
        qa[4] = q1.x; qa[5] = q1.y; qa[6] = q1.z; qa[7] = q1.w;
    }

    if (tid < NLIST) lst[tid] = lists[g * NLIST + tid];   // beyond cnt unused
    if (tid == 255) { int c = counts[g]; cnt_s = c < NLIST ? c : NLIST; }
    __syncthreads();
    int cnt = cnt_s, ntok = cnt + 1, ig = ig_p[0];

    // stage tokens to LDS as bf16 (parallel across all threads)
    for (int i = tid; i < ntok * 32; i += 256) {
        int p = i >> 5, q = i & 31;
        const float* src = (p < cnt) ? zc_off + ((size_t)b * U_ + lst[p]) * E_
                                     : (ig ? fake : zc_on + (size_t)g * E_);
        float4 x = *(const float4*)(src + q * 8);
        float4 y = *(const float4*)(src + q * 8 + 4);
        uint4 o;
        o.x = pk2(x.x, x.y); o.y = pk2(x.z, x.w);
        o.z = pk2(y.x, y.y); o.w = pk2(y.z, y.w);
        *(uint4*)(tok + p * E_ + q * 8) = o;
    }
    __syncthreads();

    // scores: group (h = tid>>5) reduces over e via shfl width 32
    for (int p = 0; p < ntok; ++p) {
        bf16x8 tv = *(const bf16x8*)(tok + p * E_ + j * 8);
        float part = 0.f;
        #pragma unroll
        for (int k = 0; k < 8; ++k) part += ubf((ushort_t)tv[k]) * qa[k];
        #pragma unroll
        for (int off = 16; off; off >>= 1) part += __shfl_xor(part, off, 32);
        if (j == 0) sc[h * MP_ + p] = part;
    }
    __syncthreads();

    // wave-parallel softmax: 32-lane group = one head, 2 slots/lane
    {
        float v0 = (j < ntok) ? sc[h * MP_ + j] : -1e30f;
        float v1 = (j + 32 < ntok) ? sc[h * MP_ + j + 32] : -1e30f;
        float mx = fmaxf(v0, v1);
        #pragma unroll
        for (int off = 16; off; off >>= 1) mx = fmaxf(mx, __shfl_xor(mx, off, 32));
        float e0 = (j < ntok) ? __expf(v0 - mx) : 0.f;
        float e1 = (j + 32 < ntok) ? __expf(v1 - mx) : 0.f;
        float sm = e0 + e1;
        #pragma unroll
        for (int off = 16; off; off >>= 1) sm += __shfl_xor(sm, off, 32);
        float inv = 1.f / sm;
        if (j < ntok)      sc[h * MP_ + j] = e0 * inv;
        if (j + 32 < ntok) sc[h * MP_ + j + 32] = e1 * inv;
    }
    __syncthreads();

    // pooled sums: thread (h,j) owns e = j*8..j*8+7 (one ds_read_b128 per token)
    float acc[8];
    #pragma unroll
    for (int k = 0; k < 8; ++k) acc[k] = 0.f;
    for (int p = 0; p < ntok; ++p) {
        float a = sc[h * MP_ + p];
        bf16x8 tv = *(const bf16x8*)(tok + p * E_ + j * 8);
        #pragma unroll
        for (int k = 0; k < 8; ++k) acc[k] += a * ubf((ushort_t)tv[k]);
    }
    uint4 o;
    o.x = pk2(acc[0], acc[1]); o.y = pk2(acc[2], acc[3]);
    o.z = pk2(acc[4], acc[5]); o.w = pk2(acc[6], acc[7]);
    ((uint4*)(wout + (size_t)g * KDIM))[tid] = o;   // tid == h*32+j
}

// ================================================================ K3: bf16 MFMA GEMM (round-2 verbatim)
// C[8192][256] = A[8192][2048]bf16 @ B (given as BT[256][2048] bf16), fp32 out.
#define BM 64
#define BN 64
#define BK 64
#define LDB 72
__global__ __launch_bounds__(256)
void gemm_wvo(const ushort_t* __restrict__ A, const ushort_t* __restrict__ BT,
              float* __restrict__ C) {
    __shared__ ushort_t As[BM * LDB];
    __shared__ ushort_t Bs[BN * LDB];
    int tid = threadIdx.x;
    int tm = blockIdx.x >> 2, tn = blockIdx.x & 3;
    int m0 = tm * BM, n0 = tn * BN;
    int wave = tid >> 6, lane = tid & 63;
    int wr = wave >> 1, wc = wave & 1;
    int l15 = lane & 15, lg = lane >> 4;

    f32x4 acc[2][2];
    #pragma unroll
    for (int m = 0; m < 2; ++m)
        #pragma unroll
        for (int n = 0; n < 2; ++n)
            acc[m][n] = (f32x4){0.f, 0.f, 0.f, 0.f};

    int s0 = tid, s1 = tid + 256;
    int r0 = s0 >> 3, u0 = s0 & 7, r1 = s1 >> 3, u1 = s1 & 7;

    for (int kt = 0; kt < KDIM; kt += BK) {
        uint4 a0 = *(const uint4*)(A  + (size_t)(m0 + r0) * KDIM + kt + u0 * 8);
        uint4 a1 = *(const uint4*)(A  + (size_t)(m0 + r1) * KDIM + kt + u1 * 8);
        uint4 b0 = *(const uint4*)(BT + (size_t)(n0 + r0) * KDIM + kt + u0 * 8);
        uint4 b1 = *(const uint4*)(BT + (size_t)(n0 + r1) * KDIM + kt + u1 * 8);
        __syncthreads();
        *(uint4*)(As + r0 * LDB + u0 * 8) = a0;
        *(uint4*)(As + r1 * LDB + u1 * 8) = a1;
        *(uint4*)(Bs + r0 * LDB + u0 * 8) = b0;
        *(uint4*)(Bs + r1 * LDB + u1 * 8) = b1;
        __syncthreads();
        #pragma unroll
        for (int kk = 0; kk < 2; ++kk) {
            bf16x8 af[2], bfr[2];
            #pragma unroll
            for (int m = 0; m < 2; ++m)
                af[m] = *(const bf16x8*)(As + (wr * 32 + m * 16 + l15) * LDB + (kk * 4 + lg) * 8);
            #pragma unroll
            for (int n = 0; n < 2; ++n)
                bfr[n] = *(const bf16x8*)(Bs + (wc * 32 + n * 16 + l15) * LDB + (kk * 4 + lg) * 8);
            #pragma unroll
            for (int m = 0; m < 2; ++m)
                #pragma unroll
                for (int n = 0; n < 2; ++n)
                    acc[m][n] = __builtin_amdgcn_mfma_f32_16x16x32_bf16(
                        af[m], bfr[n], acc[m][n], 0, 0, 0);
        }
    }
    #pragma unroll
    for (int m = 0; m < 2; ++m)
        #pragma unroll
        for (int n = 0; n < 2; ++n)
            #pragma unroll
            for (int q = 0; q < 4; ++q) {
                int row = m0 + wr * 32 + m * 16 + lg * 4 + q;
                int col = n0 + wc * 32 + n * 16 + l15;
                C[(size_t)row * E_ + col] = acc[m][n][q];
            }
}

// ================================================================ launch
extern "C" void kernel_launch(void* const* d_in, const int* in_sizes, int n_in,
                              void* d_out, int out_size, void* d_ws, size_t ws_size,
                              hipStream_t stream) {
    const float* xc_off  = (const float*)d_in[0];
    const float* xc_on   = (const float*)d_in[1];
    const float* zc_off  = (const float*)d_in[2];
    const float* zc_on   = (const float*)d_in[3];
    const float* latents = (const float*)d_in[4];
    const float* fake    = (const float*)d_in[5];
    const float* Wq      = (const float*)d_in[6];
    const float* Wk      = (const float*)d_in[7];
    const float* Wv      = (const float*)d_in[8];
    const float* Wo      = (const float*)d_in[9];
    const int*   ig      = (const int*)d_in[10];
    float* out = (float*)d_out;

    char* ws = (char*)d_ws;
    int*      counts = (int*)(ws + WS_COUNTS);
    int*      lists  = (int*)(ws + WS_LISTS);
    float*    qk     = (float*)(ws + WS_QK);
    ushort_t* w      = (ushort_t*)(ws + WS_W);
    ushort_t* wvoT   = (ushort_t*)(ws + WS_WVOT);

    const int PASS = B_ * N_ * N_ * 2;   // 16384 floats

    hipMemsetAsync(counts, 0, GCELLS * sizeof(int), stream);
    hipMemcpyAsync(out, xc_on, (size_t)PASS * sizeof(float),
                   hipMemcpyDeviceToDevice, stream);

    // 256 build_lists + 32 prep_wvo + 256 compute_qk blocks
    mega_prep<<<544, 256, 0, stream>>>(xc_off, latents, Wq, Wk, Wv, Wo,
                                       counts, lists, qk, wvoT);

    pool_cells<<<GCELLS, 256, 0, stream>>>(zc_off, zc_on, fake, qk,
                                           counts, lists, ig, w);

    gemm_wvo<<<(GCELLS / BM) * (E_ / BN), 256, 0, stream>>>(w, wvoT, out + PASS);
}

// Round 5
// 120.381 us; speedup vs baseline: 2.0311x; 1.0442x over previous
//
#include <hip/hip_runtime.h>
#include <hip/hip_bf16.h>

#define B_   8
#define U_   8192
#define E_   256
#define N_   32
#define S_   1024
#define MP_  40
#define H_   8
#define NLIST 39
#define GCELLS (B_*S_)     // 8192
#define KDIM  (H_*E_)      // 2048

typedef unsigned short ushort_t;
using bf16x8 = __attribute__((ext_vector_type(8))) short;
using f32x4  = __attribute__((ext_vector_type(4))) float;

// ---------------- ws layout (bytes) — every offset re-added by hand ----------------
// counts 0        + 32768    -> 32768
// lists  32768    + 1277952  -> 1310720
// latb   1310720  + 524288   -> 1835008   bf16 [1024][256]
// wqkT   1835008  + 1048576  -> 2883584   bf16 [2048][256]
// wvoT   2883584  + 1048576  -> 3932160   bf16 [256][2048]
// qkb    3932160  + 4194304  -> 8126464   bf16 [1024][2048]   (r3 bug: was 3931136 -> 1KB overlap)
// w      8126464  + 33554432 -> 41680896  bf16 [8192][2048]
#define WS_COUNTS 0u
#define WS_LISTS  32768u
#define WS_LATB   1310720u
#define WS_WQKT   1835008u
#define WS_WVOT   2883584u
#define WS_QKB    3932160u
#define WS_W      8126464u

__device__ inline unsigned pk2(float a, float b) {
    __hip_bfloat16 x = __float2bfloat16(a), y = __float2bfloat16(b);
    return ((unsigned)(*(ushort_t*)&y) << 16) | (unsigned)(*(ushort_t*)&x);
}
__device__ inline float ubf(ushort_t u) {
    unsigned v = (unsigned)u << 16;
    return *(float*)&v;
}

// ================================================================ K1: fused prep
// blocks [0,256): build_lists     [256,384): latents->bf16
// [384,448): WqkT[(h,e)][f]       [448,480): WvoT[e'][(h,e)]
__global__ __launch_bounds__(256)
void mega_prep(const float* __restrict__ xc_off, const float* __restrict__ latents,
               const float* __restrict__ Wq, const float* __restrict__ Wk,
               const float* __restrict__ Wv, const float* __restrict__ Wo,
               int* __restrict__ counts, int* __restrict__ lists,
               ushort_t* __restrict__ latb, ushort_t* __restrict__ wqkT,
               ushort_t* __restrict__ wvoT) {
    __shared__ float smem[10496];   // 42 KB, reused per branch
    int blk = blockIdx.x, tid = threadIdx.x;

    if (blk < 256) {                                    // ---- build_lists (r4 verbatim)
        int t = blk * 256 + tid;
        float x = xc_off[2 * t], y = xc_off[2 * t + 1];
        int row = (int)rintf(x * 31.f); row = min(max(row, 0), 31);
        int col = (int)rintf(y * 31.f); col = min(max(col, 0), 31);
        int b = t >> 13;
        int g = b * S_ + row * N_ + col;
        int old = atomicAdd(&counts[g], 1);
        if (old < NLIST) lists[g * NLIST + old] = t & (U_ - 1);
    } else if (blk < 384) {                             // ---- latents -> bf16
        int i = (blk - 256) * 256 + tid;                // 32768 chunks of 8 floats
        const float4* src = (const float4*)latents + 2 * i;
        float4 a = src[0], c = src[1];
        uint4 o;
        o.x = pk2(a.x, a.y); o.y = pk2(a.z, a.w);
        o.z = pk2(c.x, c.y); o.w = pk2(c.z, c.w);
        ((uint4*)latb)[i] = o;
    } else if (blk < 448) {                             // ---- WqkT[(h,e)][f]
        int b2 = blk - 384, h = b2 >> 3, e0 = (b2 & 7) * 32;
        float* wq_s = smem;                             // [256][33] padded
        for (int i = tid; i < 8192; i += 256) {
            int f = i >> 5, d = i & 31;
            wq_s[f * 33 + d] = Wq[f * E_ + h * 32 + d];
        }
        __syncthreads();
        int e = e0 + (tid >> 3), fg = tid & 7;
        float wk[32];
        #pragma unroll
        for (int d4 = 0; d4 < 8; ++d4) {
            float4 v = *(const float4*)(Wk + (size_t)e * E_ + h * 32 + d4 * 4);
            wk[d4*4] = v.x; wk[d4*4+1] = v.y; wk[d4*4+2] = v.z; wk[d4*4+3] = v.w;
        }
        const float invs = 0.17677669529663687f;        // 1/sqrt(32)
        ushort_t* dst = wqkT + (size_t)(h * E_ + e) * E_ + fg * 32;
        for (int q8 = 0; q8 < 4; ++q8) {
            float t8[8];
            #pragma unroll
            for (int k = 0; k < 8; ++k) {
                int f = fg * 32 + q8 * 8 + k;
                float acc = 0.f;
                #pragma unroll
                for (int d = 0; d < 32; ++d) acc += wq_s[f * 33 + d] * wk[d];
                t8[k] = acc * invs;
            }
            uint4 o;
            o.x = pk2(t8[0], t8[1]); o.y = pk2(t8[2], t8[3]);
            o.z = pk2(t8[4], t8[5]); o.w = pk2(t8[6], t8[7]);
            *(uint4*)(dst + q8 * 8) = o;
        }
    } else {                                            // ---- WvoT[e'][(h,e)]
        int b3 = blk - 448, h = b3 >> 2, e0p = (b3 & 3) * 64;
        float* wv_s = smem;                             // [256][33] padded
        float* wo_s = smem + 8448;                      // [32][64]
        for (int i = tid; i < 8192; i += 256) {
            int e = i >> 5, d = i & 31;
            wv_s[e * 33 + d] = Wv[e * E_ + h * 32 + d];
        }
        for (int i = tid; i < 2048; i += 256) {
            int d = i >> 6, el = i & 63;
            wo_s[i] = Wo[(h * 32 + d) * E_ + e0p + el];
        }
        __syncthreads();
        int erow = tid >> 2, eg = tid & 3;
        float wor[32];
        #pragma unroll
        for (int d = 0; d < 32; ++d) wor[d] = wo_s[d * 64 + erow];
        ushort_t* dst = wvoT + (size_t)(e0p + erow) * KDIM + h * E_ + eg * 64;
        for (int q8 = 0; q8 < 8; ++q8) {
            float t8[8];
            #pragma unroll
            for (int k = 0; k < 8; ++k) {
                int e = eg * 64 + q8 * 8 + k;
                float acc = 0.f;
                #pragma unroll
                for (int d = 0; d < 32; ++d) acc += wv_s[e * 33 + d] * wor[d];
                t8[k] = acc;
            }
            uint4 o;
            o.x = pk2(t8[0], t8[1]); o.y = pk2(t8[2], t8[3]);
            o.z = pk2(t8[4], t8[5]); o.w = pk2(t8[6], t8[7]);
            *(uint4*)(dst + q8 * 8) = o;
        }
    }
}

// ================================================================ K2/K4: bf16 MFMA GEMM
// C[M][N] = A[M][K] @ B given as BT[N][K].  BK=64 structure == r2/r4-verified gemm_wvo.
template<bool BF16OUT>
__global__ __launch_bounds__(256)
void gemm_k(const ushort_t* __restrict__ A, const ushort_t* __restrict__ BT,
            void* __restrict__ Cv, int Kdim, int Ndim) {
    constexpr int LDB = 72;
    __shared__ ushort_t As[64 * LDB];
    __shared__ ushort_t Bs[64 * LDB];
    int tid = threadIdx.x;
    int m0 = blockIdx.y * 64, n0 = blockIdx.x * 64;
    int wave = tid >> 6, lane = tid & 63;
    int wr = wave >> 1, wc = wave & 1;
    int l15 = lane & 15, lg = lane >> 4;

    f32x4 acc[2][2];
    #pragma unroll
    for (int m = 0; m < 2; ++m)
        #pragma unroll
        for (int n = 0; n < 2; ++n)
            acc[m][n] = (f32x4){0.f, 0.f, 0.f, 0.f};

    int s0 = tid, s1 = tid + 256;
    int r0 = s0 >> 3, u0 = s0 & 7, r1 = s1 >> 3, u1 = s1 & 7;

    for (int kt = 0; kt < Kdim; kt += 64) {
        uint4 a0 = *(const uint4*)(A  + (size_t)(m0 + r0) * Kdim + kt + u0 * 8);
        uint4 a1 = *(const uint4*)(A  + (size_t)(m0 + r1) * Kdim + kt + u1 * 8);
        uint4 b0 = *(const uint4*)(BT + (size_t)(n0 + r0) * Kdim + kt + u0 * 8);
        uint4 b1 = *(const uint4*)(BT + (size_t)(n0 + r1) * Kdim + kt + u1 * 8);
        __syncthreads();
        *(uint4*)(As + r0 * LDB + u0 * 8) = a0;
        *(uint4*)(As + r1 * LDB + u1 * 8) = a1;
        *(uint4*)(Bs + r0 * LDB + u0 * 8) = b0;
        *(uint4*)(Bs + r1 * LDB + u1 * 8) = b1;
        __syncthreads();
        #pragma unroll
        for (int kk = 0; kk < 2; ++kk) {
            bf16x8 af[2], bfr[2];
            #pragma unroll
            for (int m = 0; m < 2; ++m)
                af[m] = *(const bf16x8*)(As + (wr * 32 + m * 16 + l15) * LDB + (kk * 4 + lg) * 8);
            #pragma unroll
            for (int n = 0; n < 2; ++n)
                bfr[n] = *(const bf16x8*)(Bs + (wc * 32 + n * 16 + l15) * LDB + (kk * 4 + lg) * 8);
            #pragma unroll
            for (int m = 0; m < 2; ++m)
                #pragma unroll
                for (int n = 0; n < 2; ++n)
                    acc[m][n] = __builtin_amdgcn_mfma_f32_16x16x32_bf16(
                        af[m], bfr[n], acc[m][n], 0, 0, 0);
        }
    }
    #pragma unroll
    for (int m = 0; m < 2; ++m)
        #pragma unroll
        for (int n = 0; n < 2; ++n)
            #pragma unroll
            for (int q = 0; q < 4; ++q) {
                int row = m0 + wr * 32 + m * 16 + lg * 4 + q;
                int col = n0 + wc * 32 + n * 16 + l15;
                if (BF16OUT) {
                    __hip_bfloat16 hb = __float2bfloat16(acc[m][n][q]);
                    ((ushort_t*)Cv)[(size_t)row * Ndim + col] = *(ushort_t*)&hb;
                } else {
                    ((float*)Cv)[(size_t)row * Ndim + col] = acc[m][n][q];
                }
            }
}

// ================================================================ K3: pool (r4 verbatim, bf16 qk read)
__global__ __launch_bounds__(256)
void pool_cells(const float* __restrict__ zc_off, const float* __restrict__ zc_on,
                const float* __restrict__ fake, const ushort_t* __restrict__ qkb,
                const int* __restrict__ counts, const int* __restrict__ lists,
                const int* __restrict__ ig_p, ushort_t* __restrict__ wout) {
    __shared__ __align__(16) ushort_t tok[MP_ * E_];   // 20 KB
    __shared__ float sc[H_ * MP_];
    __shared__ int lst[NLIST];
    __shared__ int cnt_s;

    int g = blockIdx.x, s = g & (S_ - 1), b = g >> 10, tid = threadIdx.x;
    int h = tid >> 5, j = tid & 31;

    // per-thread bf16 qk fragment (e = j*8 .. j*8+7), 16B/lane
    float qa[8];
    {
        bf16x8 qv = *(const bf16x8*)(qkb + (size_t)s * KDIM + h * E_ + j * 8);
        #pragma unroll
        for (int k = 0; k < 8; ++k) qa[k] = ubf((ushort_t)qv[k]);
    }

    if (tid < NLIST) lst[tid] = lists[g * NLIST + tid];
    if (tid == 255) { int c = counts[g]; cnt_s = c < NLIST ? c : NLIST; }
    __syncthreads();
    int cnt = cnt_s, ntok = cnt + 1, ig = ig_p[0];

    // stage tokens to LDS as bf16
    for (int i = tid; i < ntok * 32; i += 256) {
        int p = i >> 5, q = i & 31;
        const float* src = (p < cnt) ? zc_off + ((size_t)b * U_ + lst[p]) * E_
                                     : (ig ? fake : zc_on + (size_t)g * E_);
        float4 x = *(const float4*)(src + q * 8);
        float4 y = *(const float4*)(src + q * 8 + 4);
        uint4 o;
        o.x = pk2(x.x, x.y); o.y = pk2(x.z, x.w);
        o.z = pk2(y.x, y.y); o.w = pk2(y.z, y.w);
        *(uint4*)(tok + p * E_ + q * 8) = o;
    }
    __syncthreads();

    // scores
    for (int p = 0; p < ntok; ++p) {
        bf16x8 tv = *(const bf16x8*)(tok + p * E_ + j * 8);
        float part = 0.f;
        #pragma unroll
        for (int k = 0; k < 8; ++k) part += ubf((ushort_t)tv[k]) * qa[k];
        #pragma unroll
        for (int off = 16; off; off >>= 1) part += __shfl_xor(part, off, 32);
        if (j == 0) sc[h * MP_ + p] = part;
    }
    __syncthreads();

    // wave-parallel softmax
    {
        float v0 = (j < ntok) ? sc[h * MP_ + j] : -1e30f;
        float v1 = (j + 32 < ntok) ? sc[h * MP_ + j + 32] : -1e30f;
        float mx = fmaxf(v0, v1);
        #pragma unroll
        for (int off = 16; off; off >>= 1) mx = fmaxf(mx, __shfl_xor(mx, off, 32));
        float e0 = (j < ntok) ? __expf(v0 - mx) : 0.f;
        float e1 = (j + 32 < ntok) ? __expf(v1 - mx) : 0.f;
        float sm = e0 + e1;
        #pragma unroll
        for (int off = 16; off; off >>= 1) sm += __shfl_xor(sm, off, 32);
        float inv = 1.f / sm;
        if (j < ntok)      sc[h * MP_ + j] = e0 * inv;
        if (j + 32 < ntok) sc[h * MP_ + j + 32] = e1 * inv;
    }
    __syncthreads();

    // pooled sums
    float acc[8];
    #pragma unroll
    for (int k = 0; k < 8; ++k) acc[k] = 0.f;
    for (int p = 0; p < ntok; ++p) {
        float a = sc[h * MP_ + p];
        bf16x8 tv = *(const bf16x8*)(tok + p * E_ + j * 8);
        #pragma unroll
        for (int k = 0; k < 8; ++k) acc[k] += a * ubf((ushort_t)tv[k]);
    }
    uint4 o;
    o.x = pk2(acc[0], acc[1]); o.y = pk2(acc[2], acc[3]);
    o.z = pk2(acc[4], acc[5]); o.w = pk2(acc[6], acc[7]);
    ((uint4*)(wout + (size_t)g * KDIM))[tid] = o;
}

// ================================================================ launch
extern "C" void kernel_launch(void* const* d_in, const int* in_sizes, int n_in,
                              void* d_out, int out_size, void* d_ws, size_t ws_size,
                              hipStream_t stream) {
    const float* xc_off  = (const float*)d_in[0];
    const float* xc_on   = (const float*)d_in[1];
    const float* zc_off  = (const float*)d_in[2];
    const float* zc_on   = (const float*)d_in[3];
    const float* latents = (const float*)d_in[4];
    const float* Wq      = (const float*)d_in[6];
    const float* Wk      = (const float*)d_in[7];
    const float* Wv      = (const float*)d_in[8];
    const float* Wo      = (const float*)d_in[9];
    const float* fake    = (const float*)d_in[5];
    const int*   ig      = (const int*)d_in[10];
    float* out = (float*)d_out;

    char* ws = (char*)d_ws;
    int*      counts = (int*)(ws + WS_COUNTS);
    int*      lists  = (int*)(ws + WS_LISTS);
    ushort_t* latb   = (ushort_t*)(ws + WS_LATB);
    ushort_t* wqkT   = (ushort_t*)(ws + WS_WQKT);
    ushort_t* wvoT   = (ushort_t*)(ws + WS_WVOT);
    ushort_t* qkb    = (ushort_t*)(ws + WS_QKB);
    ushort_t* w      = (ushort_t*)(ws + WS_W);

    const int PASS = B_ * N_ * N_ * 2;   // 16384 floats

    hipMemsetAsync(counts, 0, GCELLS * sizeof(int), stream);
    hipMemcpyAsync(out, xc_on, (size_t)PASS * sizeof(float),
                   hipMemcpyDeviceToDevice, stream);

    mega_prep<<<480, 256, 0, stream>>>(xc_off, latents, Wq, Wk, Wv, Wo,
                                       counts, lists, latb, wqkT, wvoT);

    dim3 gq(KDIM / 64, 1024 / 64);       // qkb = latb @ WqkT : M=1024 N=2048 K=256
    gemm_k<true><<<gq, 256, 0, stream>>>(latb, wqkT, qkb, 256, KDIM);

    pool_cells<<<GCELLS, 256, 0, stream>>>(zc_off, zc_on, fake, qkb,
                                           counts, lists, ig, w);

    dim3 gw(E_ / 64, GCELLS / 64);       // out = w @ Wvo : M=8192 N=256 K=2048
    gemm_k<false><<<gw, 256, 0, stream>>>(w, wvoT, out + PASS, KDIM, E_);
}